// Round 4
// baseline (77.519 us; speedup 1.0000x reference)
//
#include <hip/hip_runtime.h>
#include <stdint.h>

// QuadraticConv2DTranspose, stride 2, k=3, as fused-class bf16 MFMA GEMM.
// Bed-of-nails upsample => the four output parity classes (EE,EO,OE,OO) have
// 2/5/5/14 live features, ALL drawn from products of the same 2x2 input
// window {w00,w01,w10,w11} (+ pixel-independent bias). Round 4 fuses all 4
// classes into one block: x-tile staged once, the 14 distinct products built
// once per k-chunk, 26 (class,feature) MFMA steps with data-independent
// B-frag loads from a pre-transposed bf16 weight tensor wt[l][n][c].

typedef __attribute__((ext_vector_type(8))) short short8;
typedef __attribute__((ext_vector_type(4))) short short4v;
typedef __attribute__((ext_vector_type(4))) float floatx4;

__device__ __forceinline__ short f2bf(float f) {  // RTN-even (prologue)
  union { float f; uint32_t u; } v{f};
  uint32_t u = v.u;
  u += 0x7fffu + ((u >> 16) & 1u);
  return (short)(u >> 16);
}

// Pack bf16(a) (low) | bf16(b) (high), round-half-up: 2 adds + 1 v_perm.
__device__ __forceinline__ uint32_t pk2bf(float a, float b) {
  union { float f; uint32_t u; } x{a}, y{b};
  return __builtin_amdgcn_perm(y.u + 0x8000u, x.u + 0x8000u, 0x07060302u);
}

// 14 products over window values w[0]=(dy0,dx0) .. w[3]=(dy1,dx1):
// p0..p9 = upper-tri pairs (QA,QB); p10..p13 = linear w0..w3.
__constant__ __device__ const int cQA[10] = {0, 0, 0, 0, 1, 1, 1, 2, 2, 3};
__constant__ __device__ const int cQB[10] = {0, 1, 2, 3, 1, 2, 3, 2, 3, 3};
// 26 (product, class, kernel-row) steps; class: 0=EE 1=EO 2=OE 3=OO
// (cls bit1 = ho parity, bit0 = wo parity).
__constant__ __device__ const int cPP[26] = {0, 0, 0, 0, 1, 1, 2, 2, 3, 4, 4, 5, 6,
                                             7, 7, 8, 9, 10, 10, 10, 10, 11, 11, 12, 12, 13};
__constant__ __device__ const int cPC[26] = {0, 1, 2, 3, 1, 3, 2, 3, 3, 1, 3, 3, 3,
                                             2, 3, 3, 3, 0, 1, 2, 3, 1, 3, 2, 3, 3};
__constant__ __device__ const int cPL[26] = {30, 24, 9, 0, 26, 2, 15, 6, 8, 35, 17, 21, 23,
                                             42, 39, 41, 44, 49, 48, 46, 45, 50, 47, 52, 51, 53};

// Prologue: wt[(l*64+n)*64+c] = bf16(kern[(l*64+c)*64+n]); block 54 also
// reduces bias[n] = sum_c kern[54][c][n].
__global__ __launch_bounds__(256) void prep_w(const float* __restrict__ kern,
                                              short* __restrict__ wt,
                                              float* __restrict__ bias) {
  __shared__ float s[64][65];
  const int l = blockIdx.x;
  const int tid = threadIdx.x;
  for (int i = tid; i < 4096; i += 256)
    s[i >> 6][i & 63] = kern[(l << 12) + i];
  __syncthreads();
  if (l == 54 && tid < 64) {
    float a = 0.f;
    for (int c = 0; c < 64; ++c) a += s[c][tid];
    bias[tid] = a;
  }
  for (int i = tid; i < 1024; i += 256) {
    const int n = i >> 4, c4 = (i & 15) * 4;
    short4v v;
    v[0] = f2bf(s[c4 + 0][n]);
    v[1] = f2bf(s[c4 + 1][n]);
    v[2] = f2bf(s[c4 + 2][n]);
    v[3] = f2bf(s[c4 + 3][n]);
    *(short4v*)&wt[((l << 6) + n) * 64 + c4] = v;
  }
}

__global__ __launch_bounds__(512, 2) void qct_main(const float* __restrict__ x,
                                                   const short* __restrict__ wt,
                                                   const float* __restrict__ bias,
                                                   float* __restrict__ out) {
  __shared__ float sX[45][68];  // 5x9 positions x 64 ch fp32; stride 68 -> 2-way (free)
  const int tid = threadIdx.x;
  const int bid = blockIdx.x;
  const int b = bid >> 5, tile = bid & 31;
  const int hi0 = (tile >> 2) * 4;  // 4x8 class-pixel tile, +1 halo => 5x9 input
  const int wi0 = (tile & 3) * 8;

  // Stage x tile once for ALL classes (zero-fill OOB handles boundaries).
  for (int i = tid; i < 720; i += 512) {
    const int pos = i >> 4, c4 = (i & 15) * 4;
    const int hr = hi0 + pos / 9, wc = wi0 + pos % 9;
    float4 v = make_float4(0.f, 0.f, 0.f, 0.f);
    if (hr < 32 && wc < 32)
      v = *(const float4*)&x[(((b * 32) + hr) * 32 + wc) * 64 + c4];
    *(float4*)&sX[pos][c4] = v;
  }

  const int wave = tid >> 6, lane = tid & 63;
  const int quad = lane >> 4, l16 = lane & 15;
  const int mh = wave >> 2;  // m-half: pixels mh*16..mh*16+15 (twin waves share B -> L1)
  const int nt = wave & 3;   // n-tile of 16 couts
  const int n = nt * 16 + l16;
  const int p = mh * 16 + l16;          // this lane's A-row pixel
  const int ph = p >> 3, pw = p & 7;    // position in 4x8 tile
  const int c8 = quad * 8;              // k-offset: k = quad*8 + j

  floatx4 acc[4];
  {
    const float bv = bias[n];  // C/D col = n for all rows
    acc[0] = acc[1] = acc[2] = acc[3] = floatx4{bv, bv, bv, bv};
  }

  __syncthreads();  // the only barrier

#pragma unroll
  for (int chalf = 0; chalf < 2; ++chalf) {
    const int cb = chalf * 32 + c8;
    // 2x2 window values, 8 channels each.
    float v[4][8];
#pragma unroll
    for (int dy = 0; dy < 2; ++dy)
#pragma unroll
      for (int dx = 0; dx < 2; ++dx) {
        const int pa = (ph + dy) * 9 + (pw + dx);
        *(float4*)&v[dy * 2 + dx][0] = *(const float4*)&sX[pa][cb];
        *(float4*)&v[dy * 2 + dx][4] = *(const float4*)&sX[pa][cb + 4];
      }
    // 14 shared bf16 products (A-frags), built once for all 4 classes.
    short8 pr[14];
#pragma unroll
    for (int q = 0; q < 10; ++q) {
      union { uint32_t w[4]; short8 s; } u;
#pragma unroll
      for (int h = 0; h < 4; ++h)
        u.w[h] = pk2bf(v[cQA[q]][2 * h] * v[cQB[q]][2 * h],
                       v[cQA[q]][2 * h + 1] * v[cQB[q]][2 * h + 1]);
      pr[q] = u.s;
    }
#pragma unroll
    for (int t = 0; t < 4; ++t) {
      union { uint32_t w[4]; short8 s; } u;
#pragma unroll
      for (int h = 0; h < 4; ++h)
        u.w[h] = pk2bf(v[t][2 * h], v[t][2 * h + 1]);
      pr[10 + t] = u.s;
    }
    // 26 MFMA steps; B addresses data-independent -> pipelined; 4 acc chains
    // interleaved (product-major order) to hide MFMA latency.
#pragma unroll
    for (int s = 0; s < 26; ++s) {
      const short8 bf =
          *(const short8*)&wt[((cPL[s] * 64) + n) * 64 + chalf * 32 + c8];
      acc[cPC[s]] =
          __builtin_amdgcn_mfma_f32_16x16x32_bf16(pr[cPP[s]], bf, acc[cPC[s]], 0, 0, 0);
    }
  }

  // Epilogue. D: col = n, row = quad*4 + r -> pixel mm; class sets parity.
#pragma unroll
  for (int cls = 0; cls < 4; ++cls) {
    const int rh = cls >> 1, rw = cls & 1;
#pragma unroll
    for (int r = 0; r < 4; ++r) {
      const int mm = mh * 16 + quad * 4 + r;
      const int hi = hi0 + (mm >> 3), wi = wi0 + (mm & 7);
      const int ho = 2 * hi + rh, wo = 2 * wi + rw;
      out[(((b * 64) + ho) * 64 + wo) * 64 + n] = acc[cls][r];
    }
  }
}

extern "C" void kernel_launch(void* const* d_in, const int* in_sizes, int n_in,
                              void* d_out, int out_size, void* d_ws,
                              size_t ws_size, hipStream_t stream) {
  const float* x = (const float*)d_in[0];     // [8,32,32,64] f32
  const float* kern = (const float*)d_in[1];  // [55,64,64]   f32
  float* out = (float*)d_out;                 // [8,64,64,64] f32
  short* wt = (short*)d_ws;                   // 55*64*64 bf16
  float* bias = (float*)((char*)d_ws + 55 * 64 * 64 * 2);

  prep_w<<<55, 256, 0, stream>>>(kern, wt, bias);
  // 256 blocks x 512 threads: uniform work (all classes fused), 1 block/CU,
  // 8 waves = 2/SIMD; twin m-half waves share B rows via L1.
  qct_main<<<256, 512, 0, stream>>>(x, wt, bias, out);
}